// Round 5
// baseline (452.363 us; speedup 1.0000x reference)
//
#include <hip/hip_runtime.h>

#define N_NODES 100000
#define EMB 64
#define N_EDGES 1280000
#define N_E4 (N_EDGES / 4)     // 320000 int4 groups
#define SCAN_TILE 1024          // nodes per scan block (256 threads x 4)
#define SLICE_F16 (N_NODES * 16)  // f16 elements per 16-dim slice table (3.2 MB)

// counting-sort CSR build (no global atomics)
#define NBUCK 196               // buckets of 512 nodes: dst >> 9
#define BUCK_SHIFT 9
#define BUCK_NODES 512
#define NBA 313                 // ceil(N_EDGES / 4096)
#define HTOT (NBUCK * NBA)      // 61348 hist entries
#define NBH ((HTOT + 1023) / 1024)  // 60 hist-scan blocks

typedef unsigned long long u64;
typedef _Float16 f16;
typedef __attribute__((ext_vector_type(2))) _Float16 f16x2;
typedef __attribute__((ext_vector_type(2))) float f32x2;   // plain clang vector:
                                                           // __builtin_nontemporal_load-safe

// ---- A1: per-block bucket histogram (LDS atomics only) ----
__global__ void bucket_hist_kernel(const int* __restrict__ dst, int* __restrict__ hist) {
    __shared__ int lh[NBUCK];
    for (int i = threadIdx.x; i < NBUCK; i += 256) lh[i] = 0;
    __syncthreads();
#pragma unroll
    for (int k = 0; k < 4; ++k) {
        int q = blockIdx.x * 1024 + k * 256 + threadIdx.x;  // int4 index, coalesced
        if (q < N_E4) {
            int4 d4 = ((const int4*)dst)[q];
            atomicAdd(&lh[d4.x >> BUCK_SHIFT], 1);
            atomicAdd(&lh[d4.y >> BUCK_SHIFT], 1);
            atomicAdd(&lh[d4.z >> BUCK_SHIFT], 1);
            atomicAdd(&lh[d4.w >> BUCK_SHIFT], 1);
        }
    }
    __syncthreads();
    for (int i = threadIdx.x; i < NBUCK; i += 256)
        hist[i * NBA + blockIdx.x] = lh[i];   // bucket-major layout for the scan
}

// ---- A2a: hierarchical scan pass 1 over hist (in-place) + block sums ----
__global__ void hist_scan1_kernel(int* __restrict__ hist, int* __restrict__ hbs) {
    __shared__ int lds[256];
    int base = blockIdx.x * 1024;
    int vals[4];
    int tsum = 0;
#pragma unroll
    for (int k = 0; k < 4; ++k) {
        int i = base + threadIdx.x * 4 + k;
        vals[k] = (i < HTOT) ? hist[i] : 0;
        tsum += vals[k];
    }
    lds[threadIdx.x] = tsum;
    __syncthreads();
    for (int off = 1; off < 256; off <<= 1) {
        int v = (threadIdx.x >= (unsigned)off) ? lds[threadIdx.x - off] : 0;
        __syncthreads();
        lds[threadIdx.x] += v;
        __syncthreads();
    }
    int run = lds[threadIdx.x] - tsum;      // local exclusive base
    if (threadIdx.x == 255) hbs[blockIdx.x] = lds[255];
    #pragma unroll
    for (int k = 0; k < 4; ++k) {
        int i = base + threadIdx.x * 4 + k;
        if (i < HTOT) hist[i] = run;        // in-place: own entries only
        run += vals[k];
    }
}

// ---- A2b: exclusive scan of the 60 hist block sums (tiny) ----
// Consumers (A3, B1) add hbs[idx>>10] at read time -> no third pass.
__global__ void hist_scan2_kernel(int* __restrict__ hbs) {
    __shared__ int lds[64];
    int v = (threadIdx.x < (unsigned)NBH) ? hbs[threadIdx.x] : 0;
    lds[threadIdx.x] = v;
    __syncthreads();
    for (int off = 1; off < 64; off <<= 1) {
        int t = (threadIdx.x >= (unsigned)off) ? lds[threadIdx.x - off] : 0;
        __syncthreads();
        lds[threadIdx.x] += t;
        __syncthreads();
    }
    if (threadIdx.x < (unsigned)NBH) hbs[threadIdx.x] = lds[threadIdx.x] - v;
}

// ---- A3: scatter edges into bucket-contiguous arrays (LDS cursors) ----
__global__ void bucket_scatter_kernel(const int* __restrict__ src, const int* __restrict__ dst,
                                      const int* __restrict__ hist, const int* __restrict__ hbs,
                                      int* __restrict__ bsrc, int* __restrict__ bdst) {
    __shared__ int cur[NBUCK];
    for (int i = threadIdx.x; i < NBUCK; i += 256) {
        int idx = i * NBA + blockIdx.x;
        cur[i] = hist[idx] + hbs[idx >> 10];
    }
    __syncthreads();
#pragma unroll
    for (int k = 0; k < 4; ++k) {
        int q = blockIdx.x * 1024 + k * 256 + threadIdx.x;
        if (q < N_E4) {
            int4 d4 = ((const int4*)dst)[q];
            int4 s4 = ((const int4*)src)[q];
            int p;
            p = atomicAdd(&cur[d4.x >> BUCK_SHIFT], 1); bsrc[p] = s4.x; bdst[p] = d4.x;
            p = atomicAdd(&cur[d4.y >> BUCK_SHIFT], 1); bsrc[p] = s4.y; bdst[p] = d4.y;
            p = atomicAdd(&cur[d4.z >> BUCK_SHIFT], 1); bsrc[p] = s4.z; bdst[p] = d4.z;
            p = atomicAdd(&cur[d4.w >> BUCK_SHIFT], 1); bsrc[p] = s4.w; bdst[p] = d4.w;
        }
    }
}

// ---- B1: per-bucket node histogram; LDS atomic RETURN = per-node rank.
// Also emits deg / dinv / rdinv (norm fused: deg is already in LDS here). ----
__global__ void bucket_rank_kernel(const int* __restrict__ hist, const int* __restrict__ hbs,
                                   const int* __restrict__ bdst,
                                   int* __restrict__ brank, int* __restrict__ deg,
                                   float* __restrict__ dinv, float* __restrict__ rdinv) {
    __shared__ int lh[BUCK_NODES];
    int k = blockIdx.x;
    int i0 = k * NBA;
    int beg = hist[i0] + hbs[i0 >> 10];
    int end;
    if (k + 1 < NBUCK) {
        int i1 = (k + 1) * NBA;
        end = hist[i1] + hbs[i1 >> 10];
    } else {
        end = N_EDGES;
    }
    for (int i = threadIdx.x; i < BUCK_NODES; i += 256) lh[i] = 0;
    __syncthreads();
    for (int i = beg + threadIdx.x; i < end; i += 256) {
        int d = bdst[i];
        brank[i] = atomicAdd(&lh[d & (BUCK_NODES - 1)], 1);
    }
    __syncthreads();
    int nbase = k * BUCK_NODES;
    for (int i = threadIdx.x; i < BUCK_NODES; i += 256) {
        int nn = nbase + i;
        if (nn < N_NODES) {
            int d = lh[i];
            deg[nn] = d;
            float fd = (float)d;
            dinv[nn]  = (d > 0) ? rsqrtf(fd) : 0.0f;
            rdinv[nn] = (d > 0) ? sqrtf(fd) : 0.0f;
        }
    }
}

// ---- B2: CSR fill, atomic-free; bucket-local row_start gathers + col writes ----
__global__ void csr_fill_kernel(const int* __restrict__ row_start, const int* __restrict__ bdst,
                                const int* __restrict__ brank, const int* __restrict__ bsrc,
                                int* __restrict__ col) {
    int q = blockIdx.x * blockDim.x + threadIdx.x;
    if (q < N_E4) {
        int4 d4 = ((const int4*)bdst)[q];
        int4 r4 = ((const int4*)brank)[q];
        int4 s4 = ((const int4*)bsrc)[q];
        col[row_start[d4.x] + r4.x] = s4.x;
        col[row_start[d4.y] + r4.y] = s4.y;
        col[row_start[d4.z] + r4.z] = s4.z;
        col[row_start[d4.w] + r4.w] = s4.w;
    }
}

// ---- y0 = dinv * emb, fp16, SLICE-MAJOR layout: y[slice][node][16 dims] ----
__global__ void y0_kernel(const float* __restrict__ emb, const float* __restrict__ dinv,
                          f16* __restrict__ y0) {
    int t = blockIdx.x * blockDim.x + threadIdx.x;
    if (t < N_NODES * 4) {
        int slice = t & 3;
        int row = t >> 2;
        float dv = dinv[row];
        const float4* e = (const float4*)(emb + (size_t)row * EMB + slice * 16);
        f16 h[16];
#pragma unroll
        for (int q = 0; q < 4; ++q) {
            float4 v = e[q];
            h[q * 4 + 0] = (f16)(v.x * dv);
            h[q * 4 + 1] = (f16)(v.y * dv);
            h[q * 4 + 2] = (f16)(v.z * dv);
            h[q * 4 + 3] = (f16)(v.w * dv);
        }
        int4* o = (int4*)(y0 + (size_t)slice * SLICE_F16 + (size_t)row * 16);
        o[0] = ((const int4*)h)[0];
        o[1] = ((const int4*)h)[1];
    }
}

// ---- scan pass 1: per-block local exclusive scan + block sums ----
__global__ void scan1_kernel(const int* __restrict__ deg, int* __restrict__ local_scan,
                             int* __restrict__ block_sums) {
    __shared__ int lds[256];
    int base = blockIdx.x * SCAN_TILE;
    int vals[4];
    int tsum = 0;
#pragma unroll
    for (int k = 0; k < 4; ++k) {
        int i = base + threadIdx.x * 4 + k;
        vals[k] = (i < N_NODES) ? deg[i] : 0;
        tsum += vals[k];
    }
    lds[threadIdx.x] = tsum;
    __syncthreads();
    for (int off = 1; off < 256; off <<= 1) {
        int v = (threadIdx.x >= (unsigned)off) ? lds[threadIdx.x - off] : 0;
        __syncthreads();
        lds[threadIdx.x] += v;
        __syncthreads();
    }
    int texcl = lds[threadIdx.x] - tsum;
    if (threadIdx.x == 255) block_sums[blockIdx.x] = lds[255];
    int run = texcl;
#pragma unroll
    for (int k = 0; k < 4; ++k) {
        int i = base + threadIdx.x * 4 + k;
        if (i < N_NODES) local_scan[i] = run;
        run += vals[k];
    }
}

// ---- scan pass 2: exclusive scan of the 98 block sums (single block) ----
__global__ void scan2_kernel(int* __restrict__ block_sums, int nb) {
    __shared__ int lds[128];
    int v = (threadIdx.x < (unsigned)nb) ? block_sums[threadIdx.x] : 0;
    lds[threadIdx.x] = v;
    __syncthreads();
    for (int off = 1; off < 128; off <<= 1) {
        int t = (threadIdx.x >= (unsigned)off) ? lds[threadIdx.x - off] : 0;
        __syncthreads();
        lds[threadIdx.x] += t;
        __syncthreads();
    }
    if (threadIdx.x < (unsigned)nb) block_sums[threadIdx.x] = lds[threadIdx.x] - v;
}

// ---- scan pass 3: add block offsets; cap row_start ----
__global__ void scan3_kernel(int* __restrict__ row_start, const int* __restrict__ block_sums) {
    int i = blockIdx.x * blockDim.x + threadIdx.x;
    if (i < N_NODES) {
        row_start[i] = row_start[i] + block_sums[i / SCAN_TILE];
    }
    if (i == 0) row_start[N_NODES] = N_EDGES;
}

// ---- propagation, DIM-SLICED + XCD-PINNED ----
// blockIdx & 7 = XCD (round-robin dispatch). slice k = xcd>>1 (16 dims, 3.2 MB
// table -> L2-resident per XCD), row half = xcd&1. Each wave owns one dst row:
// 8 edge-slots x 8 dim-pairs. Gathers hit the XCD's own L2; all streamed
// read-once / write-once data is nontemporal so it can't evict the table.
template <bool FINAL>
__global__ void gather_kernel(const int* __restrict__ row_start, const int* __restrict__ col,
                              const float* __restrict__ dinv, const float* __restrict__ rdinv,
                              const f16* __restrict__ yin, f16* __restrict__ yout,
                              const float* __restrict__ emb,
                              const f16* __restrict__ y1, const f16* __restrict__ y2,
                              float* __restrict__ out) {
    unsigned b = blockIdx.x;
    int xcd = b & 7;
    int k = xcd >> 1;                 // dim-slice 0..3
    int half = xcd & 1;               // row half
    unsigned row = (unsigned)half * (N_NODES / 2) + (b >> 3) * 4 + (threadIdx.x >> 6);
    int lane = threadIdx.x & 63;
    int s = lane >> 3;                // edge slot 0..7
    int j = lane & 7;                 // dim pair within slice: dims 2j, 2j+1
    int beg = row_start[row];
    int end = row_start[row + 1];
    const f16* yj = yin + (size_t)k * SLICE_F16 + 2 * j;   // + c*16 per edge
    float accx = 0.0f, accy = 0.0f;
    for (int cb = beg; cb < end; cb += 64) {   // uniform bounds
        int idx = cb + lane;
        int ci = 0;
        if (idx < end) ci = col[idx];
        int n = end - cb;
        if (n > 64) n = 64;            // uniform
        int kk = 0;
        for (; kk + 16 <= n; kk += 16) {   // 2 edges/slot in flight
            int c0 = __shfl(ci, kk + s);
            int c1 = __shfl(ci, kk + 8 + s);
            unsigned u0 = *(const unsigned*)(yj + (unsigned)c0 * 16);
            unsigned u1 = *(const unsigned*)(yj + (unsigned)c1 * 16);
            f16x2 h0 = __builtin_bit_cast(f16x2, u0);
            f16x2 h1 = __builtin_bit_cast(f16x2, u1);
            accx += (float)h0.x + (float)h1.x;
            accy += (float)h0.y + (float)h1.y;
        }
        if (kk + 8 <= n) {             // uniform
            int c0 = __shfl(ci, kk + s);
            unsigned u0 = *(const unsigned*)(yj + (unsigned)c0 * 16);
            f16x2 h0 = __builtin_bit_cast(f16x2, u0);
            accx += (float)h0.x;
            accy += (float)h0.y;
            kk += 8;
        }
        if (kk < n) {                  // tail <8 edges; shfl exec-uniform
            int c0 = __shfl(ci, (kk + s) & 63);
            if (kk + s < n) {
                unsigned u0 = *(const unsigned*)(yj + (unsigned)c0 * 16);
                f16x2 h0 = __builtin_bit_cast(f16x2, u0);
                accx += (float)h0.x;
                accy += (float)h0.y;
            }
        }
    }
    // reduce across the 8 edge slots (converged)
    accx += __shfl_xor(accx, 8);  accy += __shfl_xor(accy, 8);
    accx += __shfl_xor(accx, 16); accy += __shfl_xor(accy, 16);
    accx += __shfl_xor(accx, 32); accy += __shfl_xor(accy, 32);
    if (s == 0) {
        float dv = dinv[row];
        unsigned so = (unsigned)k * SLICE_F16 + row * 16 + 2 * (unsigned)j;  // slice-major
        if (!FINAL) {
            float sc = dv * dv;
            f16x2 h;
            h.x = (f16)(accx * sc);
            h.y = (f16)(accy * sc);
            unsigned hv = __builtin_bit_cast(unsigned, h);
            __builtin_nontemporal_store(hv, (unsigned*)(yout + so));  // NT: don't evict table
        } else {
            float rv = rdinv[row];
            unsigned od = row * EMB + (unsigned)k * 16 + 2 * (unsigned)j;    // dim-major
            f32x2 e2 = __builtin_nontemporal_load((const f32x2*)(emb + od));
            unsigned ua = __builtin_nontemporal_load((const unsigned*)(y1 + so));
            unsigned ub = __builtin_nontemporal_load((const unsigned*)(y2 + so));
            f16x2 a = __builtin_bit_cast(f16x2, ua);
            f16x2 bb = __builtin_bit_cast(f16x2, ub);
            float rx = 0.25f * (e2.x + rv * ((float)a.x + (float)bb.x) + dv * accx);
            float ry = 0.25f * (e2.y + rv * ((float)a.y + (float)bb.y) + dv * accy);
            __builtin_nontemporal_store(rx, out + od);      // out is never re-read
            __builtin_nontemporal_store(ry, out + od + 1);
        }
    }
}

extern "C" void kernel_launch(void* const* d_in, const int* in_sizes, int n_in,
                              void* d_out, int out_size, void* d_ws, size_t ws_size,
                              hipStream_t stream) {
    const int*   edge = (const int*)d_in[0];   // (2, N_EDGES) row-major
    const int*   src  = edge;
    const int*   dst  = edge + N_EDGES;
    const float* emb  = (const float*)d_in[1]; // (N_NODES, 64) fp32
    float*       out  = (float*)d_out;

    // workspace carve (16B-aligned offsets)
    char* ws = (char*)d_ws;
    size_t off = 0;
    int* deg       = (int*)(ws + off); off += 400000;
    int* row_start = (int*)(ws + off); off += 400016;
    int* bsums     = (int*)(ws + off); off += 512;
    int* hbs       = (int*)(ws + off); off += 256;   // hist-scan block sums (60)
    float* dinv    = (float*)(ws + off); off += 400000;
    float* rdinv   = (float*)(ws + off); off += 400000;
    int* hist      = (int*)(ws + off); off += (size_t)HTOT * 4 + 16;        // 245 KB
    int* col       = (int*)(ws + off); off += (size_t)N_EDGES * 4;          // 5.12 MB
    f16* y0        = (f16*)(ws + off); off += (size_t)N_NODES * EMB * 2;    // 12.8 MB
    f16* y1        = (f16*)(ws + off); off += (size_t)N_NODES * EMB * 2;    // 12.8 MB
    f16* y2        = (f16*)(ws + off); off += (size_t)N_NODES * EMB * 2;    // 12.8 MB

    // bucketed edge arrays alias y1/y2: all dead before the first gather writes y1
    // (layer 1) and before layer 2 writes y2.
    int* bsrc  = (int*)y1;                       // 5.12 MB
    int* bdst  = (int*)((char*)y1 + (size_t)N_EDGES * 4); // 5.12 MB (y1 is 12.8 MB)
    int* brank = (int*)y2;                       // 5.12 MB

    const int NB = (N_NODES + SCAN_TILE - 1) / SCAN_TILE;  // 98

    // ---- CSR build via bucketed counting sort: zero global atomics ----
    bucket_hist_kernel<<<NBA, 256, 0, stream>>>(dst, hist);
    hist_scan1_kernel<<<NBH, 256, 0, stream>>>(hist, hbs);
    hist_scan2_kernel<<<1, 64, 0, stream>>>(hbs);
    bucket_scatter_kernel<<<NBA, 256, 0, stream>>>(src, dst, hist, hbs, bsrc, bdst);
    bucket_rank_kernel<<<NBUCK, 256, 0, stream>>>(hist, hbs, bdst, brank, deg,
                                                  dinv, rdinv);
    y0_kernel<<<(N_NODES * 4 + 255) / 256, 256, 0, stream>>>(emb, dinv, y0);
    scan1_kernel<<<NB, 256, 0, stream>>>(deg, row_start, bsums);
    scan2_kernel<<<1, 128, 0, stream>>>(bsums, NB);
    scan3_kernel<<<(N_NODES + 255) / 256, 256, 0, stream>>>(row_start, bsums);
    csr_fill_kernel<<<(N_E4 + 255) / 256, 256, 0, stream>>>(row_start, bdst, brank,
                                                            bsrc, col);

    // ---- 3 propagation layers, dim-sliced; grid = 4 slices x 2 halves x chunks ----
    // 100000 blocks: xcd = b&7 -> (slice, half); b>>3 -> 4-row chunk (4 waves).
    const int gblocks = N_NODES;   // (N_NODES/2 rows / 4 per block) * 8 xcd-roles
    gather_kernel<false><<<gblocks, 256, 0, stream>>>(row_start, col, dinv, rdinv,
                                                      y0, y1, emb, y1, y2, out);
    gather_kernel<false><<<gblocks, 256, 0, stream>>>(row_start, col, dinv, rdinv,
                                                      y1, y2, emb, y1, y2, out);
    gather_kernel<true><<<gblocks, 256, 0, stream>>>(row_start, col, dinv, rdinv,
                                                     y2, (f16*)0, emb, y1, y2, out);
}

// Round 6
// 259.747 us; speedup vs baseline: 1.7415x; 1.7415x over previous
//
#include <hip/hip_runtime.h>

#define N_NODES 100000
#define EMB 64
#define N_EDGES 1280000
#define N_E4 (N_EDGES / 4)     // 320000 int4 groups

// counting-sort CSR build (no global atomics)
#define NBUCK 196               // buckets of 512 nodes: dst >> 9
#define BUCK_SHIFT 9
#define BUCK_NODES 512
#define NBA 313                 // ceil(N_EDGES / 4096)
#define HTOT (NBUCK * NBA)      // 61348 hist entries
#define NBH ((HTOT + 1023) / 1024)  // 60 hist-scan blocks

typedef unsigned long long u64;
typedef _Float16 f16;
typedef __attribute__((ext_vector_type(2))) _Float16 f16x2;

// ---- A1: per-block bucket histogram (LDS atomics only) ----
__global__ void bucket_hist_kernel(const int* __restrict__ dst, int* __restrict__ hist) {
    __shared__ int lh[NBUCK];
    for (int i = threadIdx.x; i < NBUCK; i += 256) lh[i] = 0;
    __syncthreads();
#pragma unroll
    for (int k = 0; k < 4; ++k) {
        int q = blockIdx.x * 1024 + k * 256 + threadIdx.x;  // int4 index, coalesced
        if (q < N_E4) {
            int4 d4 = ((const int4*)dst)[q];
            atomicAdd(&lh[d4.x >> BUCK_SHIFT], 1);
            atomicAdd(&lh[d4.y >> BUCK_SHIFT], 1);
            atomicAdd(&lh[d4.z >> BUCK_SHIFT], 1);
            atomicAdd(&lh[d4.w >> BUCK_SHIFT], 1);
        }
    }
    __syncthreads();
    for (int i = threadIdx.x; i < NBUCK; i += 256)
        hist[i * NBA + blockIdx.x] = lh[i];   // bucket-major layout for the scan
}

// ---- A2a: hierarchical scan pass 1 over hist (in-place) + block sums ----
__global__ void hist_scan1_kernel(int* __restrict__ hist, int* __restrict__ hbs) {
    __shared__ int lds[256];
    int base = blockIdx.x * 1024;
    int vals[4];
    int tsum = 0;
#pragma unroll
    for (int k = 0; k < 4; ++k) {
        int i = base + threadIdx.x * 4 + k;
        vals[k] = (i < HTOT) ? hist[i] : 0;
        tsum += vals[k];
    }
    lds[threadIdx.x] = tsum;
    __syncthreads();
    for (int off = 1; off < 256; off <<= 1) {
        int v = (threadIdx.x >= (unsigned)off) ? lds[threadIdx.x - off] : 0;
        __syncthreads();
        lds[threadIdx.x] += v;
        __syncthreads();
    }
    int run = lds[threadIdx.x] - tsum;      // local exclusive base
    if (threadIdx.x == 255) hbs[blockIdx.x] = lds[255];
    #pragma unroll
    for (int k = 0; k < 4; ++k) {
        int i = base + threadIdx.x * 4 + k;
        if (i < HTOT) hist[i] = run;        // in-place: own entries only
        run += vals[k];
    }
}

// ---- A2b: exclusive scan of the 60 hist block sums (tiny) ----
// Consumers (A3, B1) add hbs[idx>>10] at read time -> no third pass.
__global__ void hist_scan2_kernel(int* __restrict__ hbs) {
    __shared__ int lds[64];
    int v = (threadIdx.x < (unsigned)NBH) ? hbs[threadIdx.x] : 0;
    lds[threadIdx.x] = v;
    __syncthreads();
    for (int off = 1; off < 64; off <<= 1) {
        int t = (threadIdx.x >= (unsigned)off) ? lds[threadIdx.x - off] : 0;
        __syncthreads();
        lds[threadIdx.x] += t;
        __syncthreads();
    }
    if (threadIdx.x < (unsigned)NBH) hbs[threadIdx.x] = lds[threadIdx.x] - v;
}

// ---- A3: scatter edges into ONE bucket-contiguous packed array.
// packed = src | ((dst & 511) << 17): src < 2^17, local-dst 9 bits.
// Halves the scattered write traffic vs separate bsrc/bdst arrays. ----
__global__ void bucket_scatter_kernel(const int* __restrict__ src, const int* __restrict__ dst,
                                      const int* __restrict__ hist, const int* __restrict__ hbs,
                                      int* __restrict__ bedge) {
    __shared__ int cur[NBUCK];
    for (int i = threadIdx.x; i < NBUCK; i += 256) {
        int idx = i * NBA + blockIdx.x;
        cur[i] = hist[idx] + hbs[idx >> 10];
    }
    __syncthreads();
#pragma unroll
    for (int k = 0; k < 4; ++k) {
        int q = blockIdx.x * 1024 + k * 256 + threadIdx.x;
        if (q < N_E4) {
            int4 d4 = ((const int4*)dst)[q];
            int4 s4 = ((const int4*)src)[q];
            int p;
            p = atomicAdd(&cur[d4.x >> BUCK_SHIFT], 1);
            bedge[p] = s4.x | ((d4.x & (BUCK_NODES - 1)) << 17);
            p = atomicAdd(&cur[d4.y >> BUCK_SHIFT], 1);
            bedge[p] = s4.y | ((d4.y & (BUCK_NODES - 1)) << 17);
            p = atomicAdd(&cur[d4.z >> BUCK_SHIFT], 1);
            bedge[p] = s4.z | ((d4.z & (BUCK_NODES - 1)) << 17);
            p = atomicAdd(&cur[d4.w >> BUCK_SHIFT], 1);
            bedge[p] = s4.w | ((d4.w & (BUCK_NODES - 1)) << 17);
        }
    }
}

// ---- B: fused rank + row_start + norm + CSR fill (one block per bucket).
// row_start[node] = bucket_edge_base + LDS_exclusive_scan(per-node counts);
// col fill uses LDS cursor atomics. Replaces deg/scan1/scan2/scan3/rank/fill. ----
__global__ void bucket_build_kernel(const int* __restrict__ hist, const int* __restrict__ hbs,
                                    const int* __restrict__ bedge,
                                    int* __restrict__ col, int* __restrict__ row_start,
                                    float* __restrict__ dinv, float* __restrict__ rdinv) {
    __shared__ int lh[BUCK_NODES];
    __shared__ int sc[256];
    __shared__ int cur[BUCK_NODES];
    int k = blockIdx.x;
    int tid = threadIdx.x;
    int i0 = k * NBA;
    int beg = hist[i0] + hbs[i0 >> 10];
    int end;
    if (k + 1 < NBUCK) {
        int i1 = (k + 1) * NBA;
        end = hist[i1] + hbs[i1 >> 10];
    } else {
        end = N_EDGES;
    }
    lh[tid] = 0;
    lh[tid + 256] = 0;
    __syncthreads();
    // pass 1: per-node counts
    for (int i = beg + tid; i < end; i += 256)
        atomicAdd(&lh[((unsigned)bedge[i]) >> 17], 1);
    __syncthreads();
    // exclusive scan of 512 bins (2 per thread)
    int v0 = lh[2 * tid];
    int v1 = lh[2 * tid + 1];
    int tsum = v0 + v1;
    sc[tid] = tsum;
    __syncthreads();
    for (int off = 1; off < 256; off <<= 1) {
        int v = (tid >= off) ? sc[tid - off] : 0;
        __syncthreads();
        sc[tid] += v;
        __syncthreads();
    }
    int texcl = sc[tid] - tsum;
    cur[2 * tid] = texcl;
    cur[2 * tid + 1] = texcl + v0;
    __syncthreads();
    // row_start + norms (node 100000 cap falls out naturally in bucket 195)
    for (int i = tid; i < BUCK_NODES; i += 256) {
        int node = k * BUCK_NODES + i;
        if (node <= N_NODES) {
            row_start[node] = beg + cur[i];
            if (node < N_NODES) {
                int d = lh[i];
                float fd = (float)d;
                dinv[node]  = (d > 0) ? rsqrtf(fd) : 0.0f;
                rdinv[node] = (d > 0) ? sqrtf(fd) : 0.0f;
            }
        }
    }
    // pass 2: fill col (bucket-local window -> L2-resident)
    for (int i = beg + tid; i < end; i += 256) {
        unsigned pe = (unsigned)bedge[i];
        int r = atomicAdd(&cur[pe >> 17], 1);
        col[beg + r] = (int)(pe & 0x1FFFFu);
    }
}

// ---- y0 = dinv * emb, fp16, cached store (y0 is gathered next -> keep in L2/L3) ----
__global__ void y0_kernel(const float* __restrict__ emb, const float* __restrict__ dinv,
                          f16* __restrict__ y0) {
    int i = blockIdx.x * blockDim.x + threadIdx.x;
    const int n4 = N_NODES * EMB / 4;
    if (i < n4) {
        float dv = dinv[i >> 4];  // 16 float4s per 64-dim row
        float4 v = ((const float4*)emb)[i];
        f16 h[4] = {(f16)(v.x * dv), (f16)(v.y * dv), (f16)(v.z * dv), (f16)(v.w * dv)};
        ((u64*)y0)[i] = *(const u64*)h;
    }
}

// ---- propagation: one wave per destination row, two slots, 8-deep MLP ----
// (R3-measured structure: 52 us FINAL, near the pull-model traffic minimum)
template <bool FINAL>
__global__ void gather_kernel(const int* __restrict__ row_start, const int* __restrict__ col,
                              const float* __restrict__ dinv, const float* __restrict__ rdinv,
                              const f16* __restrict__ yin, f16* __restrict__ yout,
                              const float* __restrict__ emb,
                              const f16* __restrict__ y1, const f16* __restrict__ y2,
                              float* __restrict__ out) {
    unsigned int gid = blockIdx.x * blockDim.x + threadIdx.x;
    unsigned int row = gid >> 6;       // wave-uniform
    int lane = (int)(gid & 63u);
    int s = lane >> 5;   // edge slot 0/1
    int j = lane & 31;   // dim pair: dims 2j, 2j+1
    if (row >= N_NODES) return;        // wave-uniform exit
    int beg = row_start[row];
    int end = row_start[row + 1];
    const f16* yj = yin + 2 * j;       // lane-fixed dim offset
    float accx = 0.0f, accy = 0.0f;
    for (int cb = beg; cb < end; cb += 64) {   // uniform bounds
        int idx = cb + lane;
        int ci = 0;
        if (idx < end) ci = col[idx];
        int n = end - cb;
        if (n > 64) n = 64;            // uniform
        int kk = 0;
        for (; kk + 8 <= n; kk += 8) { // 4 edges per slot: 8 gathers in flight/wave
            int c0 = __shfl(ci, kk + s);
            int c1 = __shfl(ci, kk + s + 2);
            int c2 = __shfl(ci, kk + s + 4);
            int c3 = __shfl(ci, kk + s + 6);
            unsigned u0 = *(const unsigned*)(yj + (unsigned)c0 * EMB);
            unsigned u1 = *(const unsigned*)(yj + (unsigned)c1 * EMB);
            unsigned u2 = *(const unsigned*)(yj + (unsigned)c2 * EMB);
            unsigned u3 = *(const unsigned*)(yj + (unsigned)c3 * EMB);
            f16x2 h0 = __builtin_bit_cast(f16x2, u0);
            f16x2 h1 = __builtin_bit_cast(f16x2, u1);
            f16x2 h2 = __builtin_bit_cast(f16x2, u2);
            f16x2 h3 = __builtin_bit_cast(f16x2, u3);
            accx += (float)h0.x + (float)h1.x + (float)h2.x + (float)h3.x;
            accy += (float)h0.y + (float)h1.y + (float)h2.y + (float)h3.y;
        }
        if (kk + 4 <= n) {             // uniform
            int c0 = __shfl(ci, kk + s);
            int c1 = __shfl(ci, kk + s + 2);
            unsigned u0 = *(const unsigned*)(yj + (unsigned)c0 * EMB);
            unsigned u1 = *(const unsigned*)(yj + (unsigned)c1 * EMB);
            f16x2 h0 = __builtin_bit_cast(f16x2, u0);
            f16x2 h1 = __builtin_bit_cast(f16x2, u1);
            accx += (float)h0.x + (float)h1.x;
            accy += (float)h0.y + (float)h1.y;
            kk += 4;
        }
        for (; kk < n; ++kk) {         // <=3 edges; shfl converged, acc predicated
            int c = __shfl(ci, kk);
            if (s == (kk & 1)) {
                unsigned u = *(const unsigned*)(yj + (unsigned)c * EMB);
                f16x2 h = __builtin_bit_cast(f16x2, u);
                accx += (float)h.x;
                accy += (float)h.y;
            }
        }
    }
    // merge the two edge slots (converged)
    accx += __shfl_xor(accx, 32);
    accy += __shfl_xor(accy, 32);
    if (s == 0) {
        float dv = dinv[row];
        unsigned int o = row * EMB + 2 * (unsigned)j;
        if (!FINAL) {
            float sc = dv * dv;
            f16x2 h;
            h.x = (f16)(accx * sc);
            h.y = (f16)(accy * sc);
            *(unsigned*)(yout + o) = __builtin_bit_cast(unsigned, h);  // cached: re-read next layer
        } else {
            float rv = rdinv[row];
            float2 e2 = *(const float2*)(emb + o);
            f16x2 a = __builtin_bit_cast(f16x2, *(const unsigned*)(y1 + o));
            f16x2 b = __builtin_bit_cast(f16x2, *(const unsigned*)(y2 + o));
            float rx = 0.25f * (e2.x + rv * ((float)a.x + (float)b.x) + dv * accx);
            float ry = 0.25f * (e2.y + rv * ((float)a.y + (float)b.y) + dv * accy);
            __builtin_nontemporal_store(rx, out + o);      // out is never re-read
            __builtin_nontemporal_store(ry, out + o + 1);
        }
    }
}

extern "C" void kernel_launch(void* const* d_in, const int* in_sizes, int n_in,
                              void* d_out, int out_size, void* d_ws, size_t ws_size,
                              hipStream_t stream) {
    const int*   edge = (const int*)d_in[0];   // (2, N_EDGES) row-major
    const int*   src  = edge;
    const int*   dst  = edge + N_EDGES;
    const float* emb  = (const float*)d_in[1]; // (N_NODES, 64) fp32
    float*       out  = (float*)d_out;

    // workspace carve (16B-aligned offsets)
    char* ws = (char*)d_ws;
    size_t off = 0;
    int* row_start = (int*)(ws + off); off += 400016;
    int* hbs       = (int*)(ws + off); off += 256;   // hist-scan block sums (60)
    float* dinv    = (float*)(ws + off); off += 400000;
    float* rdinv   = (float*)(ws + off); off += 400000;
    int* hist      = (int*)(ws + off); off += (size_t)HTOT * 4 + 16;        // 245 KB
    int* col       = (int*)(ws + off); off += (size_t)N_EDGES * 4;          // 5.12 MB
    f16* y0        = (f16*)(ws + off); off += (size_t)N_NODES * EMB * 2;    // 12.8 MB
    f16* y1        = (f16*)(ws + off); off += (size_t)N_NODES * EMB * 2;    // 12.8 MB
    f16* y2        = (f16*)(ws + off); off += (size_t)N_NODES * EMB * 2;    // 12.8 MB

    // packed edge array aliases y1: dead before layer-1 gather writes y1.
    int* bedge = (int*)y1;                       // 5.12 MB

    // ---- CSR build via bucketed counting sort: zero global atomics, 5 dispatches ----
    bucket_hist_kernel<<<NBA, 256, 0, stream>>>(dst, hist);
    hist_scan1_kernel<<<NBH, 256, 0, stream>>>(hist, hbs);
    hist_scan2_kernel<<<1, 64, 0, stream>>>(hbs);
    bucket_scatter_kernel<<<NBA, 256, 0, stream>>>(src, dst, hist, hbs, bedge);
    bucket_build_kernel<<<NBUCK, 256, 0, stream>>>(hist, hbs, bedge, col, row_start,
                                                   dinv, rdinv);
    y0_kernel<<<(N_NODES * EMB / 4 + 255) / 256, 256, 0, stream>>>(emb, dinv, y0);

    // ---- 3 propagation layers (pure y-sums), final fuses the 1/4-sum ----
    const unsigned int gthreads = (unsigned int)N_NODES * EMB;
    const int gblocks = (int)((gthreads + 255) / 256);
    gather_kernel<false><<<gblocks, 256, 0, stream>>>(row_start, col, dinv, rdinv,
                                                      y0, y1, emb, y1, y2, out);
    gather_kernel<false><<<gblocks, 256, 0, stream>>>(row_start, col, dinv, rdinv,
                                                      y1, y2, emb, y1, y2, out);
    gather_kernel<true><<<gblocks, 256, 0, stream>>>(row_start, col, dinv, rdinv,
                                                     y2, (f16*)0, emb, y1, y2, out);
}